// Round 11
// baseline (144.752 us; speedup 1.0000x reference)
//
#include <hip/hip_runtime.h>
#include <hip/hip_fp16.h>
#include <math.h>

// MS-SSIM on (16,1,512,512) fp32, 5 levels, 11x11 gaussian (sigma=1.5), 2x2 avg-pool.
// Round-11 structure (4 dispatches, all barrier-free in the hot path):
//   1) pool_all_kernel (1024 blocks): full exact-fp32 pool pyramid (R3 proven).
//   2) h_kernel (5456 blocks): ALL levels; each thread = 4 h-pixels; horizontal
//      11-tap conv of s=x+y, d=x-y, s^2, d^2 straight from global; writes fp16
//      __half2 SD/Q planes to ws (L3-resident). No LDS, no barriers.
//   3) v_kernel (5456 blocks): ALL levels; each thread = 4 output px; vertical
//      11-tap conv from the planes + SSIM/MCS via s/d identities; per-block
//      partials. Only a 32B LDS reduction buffer.
//   4) finalize_kernel.
// Rationale: R4/R9/R10 all pinned at A~44us, VALUBusy ~42% across 3 memory
// structures -> the barrier-phased block structure was the limiter, not
// latency. This decomposition has zero intra-block phase serialization.

#define WS 11

__device__ __forceinline__ void gauss_weights(float* w) {
    float s = 0.f;
#pragma unroll
    for (int j = 0; j < WS; ++j) {
        float d = (float)(j - 5);
        float e = expf(-d * d / 4.5f);   // 2*sigma^2 = 4.5
        w[j] = e;
        s += e;
    }
    float inv = 1.f / s;
#pragma unroll
    for (int j = 0; j < WS; ++j) w[j] *= inv;
}

// Block-uniform level decode for the 5456-block H/V grids.
// L0 [0,4096) L1 [4096,5120) L2 [5120,5376) L3 [5376,5440) L4 [5440,5456)
__device__ __forceinline__ void decode_lvl(
    int lin, int& level, int& b, int& pbase, int& W, int& lw, size_t& poff)
{
    int li, bl;
    if (lin < 4096)      { level = 0; li = lin;        bl = 8; W = 512; lw = 9; poff = 0; }
    else if (lin < 5120) { level = 1; li = lin - 4096; bl = 6; W = 256; lw = 8; poff = 4194304; }
    else if (lin < 5376) { level = 2; li = lin - 5120; bl = 4; W = 128; lw = 7; poff = 5242880; }
    else if (lin < 5440) { level = 3; li = lin - 5376; bl = 2; W = 64;  lw = 6; poff = 5505024; }
    else                 { level = 4; li = lin - 5440; bl = 0; W = 32;  lw = 5; poff = 5570560; }
    b = li >> bl;
    pbase = (li - (b << bl)) << 10;
}

// ---------------------------------------------------------------------------
// Kernel 1: full pool pyramid (R3 proven, absmax 0.0). Grid (8,8,16).
__global__ __launch_bounds__(256) void pool_all_kernel(
    const float* __restrict__ img1, const float* __restrict__ img2,
    float* __restrict__ l1a, float* __restrict__ l1b,
    float* __restrict__ l2a, float* __restrict__ l2b,
    float* __restrict__ l3a, float* __restrict__ l3b,
    float* __restrict__ l4a, float* __restrict__ l4b)
{
    __shared__ float buf[64 * 68];
    __shared__ float pl1[32 * 36];
    __shared__ float pl2[16 * 20];
    __shared__ float pl3[8 * 12];
    const int tid = threadIdx.x;
    const int rx = blockIdx.x, ry = blockIdx.y, b = blockIdx.z;
    const int gx0 = rx * 64, gy0 = ry * 64;

#pragma unroll 1
    for (int q = 0; q < 2; ++q) {
        const float* src = (q == 0 ? img1 : img2) + (size_t)b * 512 * 512;
        float* d1 = (q == 0 ? l1a : l1b) + (size_t)b * 256 * 256;
        float* d2 = (q == 0 ? l2a : l2b) + (size_t)b * 128 * 128;
        float* d3 = (q == 0 ? l3a : l3b) + (size_t)b * 64 * 64;
        float* d4 = (q == 0 ? l4a : l4b) + (size_t)b * 32 * 32;
        if (q) __syncthreads();
        for (int t = tid; t < 1024; t += 256) {
            int r = t >> 4, c4 = t & 15;
            float4 v = *(const float4*)(src + (size_t)(gy0 + r) * 512 + gx0 + 4 * c4);
            *(float4*)&buf[r * 68 + 4 * c4] = v;
        }
        __syncthreads();
        for (int t = tid; t < 1024; t += 256) {
            int r = t >> 5, c = t & 31;
            const float* p = &buf[(2 * r) * 68 + 2 * c];
            float v = 0.25f * ((p[0] + p[1]) + (p[68] + p[69]));
            pl1[r * 36 + c] = v;
            d1[(size_t)(32 * ry + r) * 256 + 32 * rx + c] = v;
        }
        __syncthreads();
        {
            int r = tid >> 4, c = tid & 15;
            const float* p = &pl1[(2 * r) * 36 + 2 * c];
            float v = 0.25f * ((p[0] + p[1]) + (p[36] + p[37]));
            pl2[r * 20 + c] = v;
            d2[(size_t)(16 * ry + r) * 128 + 16 * rx + c] = v;
        }
        __syncthreads();
        if (tid < 64) {
            int r = tid >> 3, c = tid & 7;
            const float* p = &pl2[(2 * r) * 20 + 2 * c];
            float v = 0.25f * ((p[0] + p[1]) + (p[20] + p[21]));
            pl3[r * 12 + c] = v;
            d3[(size_t)(8 * ry + r) * 64 + 8 * rx + c] = v;
        }
        __syncthreads();
        if (tid < 16) {
            int r = tid >> 2, c = tid & 3;
            const float* p = &pl3[(2 * r) * 12 + 2 * c];
            float v = 0.25f * ((p[0] + p[1]) + (p[12] + p[13]));
            d4[(size_t)(4 * ry + r) * 32 + 4 * rx + c] = v;
        }
    }
}

// ---------------------------------------------------------------------------
// Kernel 2: horizontal pass, all levels, no LDS, no barriers. 5456 blocks.
__global__ __launch_bounds__(256) void h_kernel(
    const float* __restrict__ img1, const float* __restrict__ img2,
    const float* __restrict__ l1a, const float* __restrict__ l1b,
    const float* __restrict__ l2a, const float* __restrict__ l2b,
    const float* __restrict__ l3a, const float* __restrict__ l3b,
    const float* __restrict__ l4a, const float* __restrict__ l4b,
    __half2* __restrict__ pSD, __half2* __restrict__ pQ)
{
    const int tid = threadIdx.x;
    const int lin = blockIdx.x;
    int level, b, pbase, W, lw; size_t poff;
    decode_lvl(lin, level, b, pbase, W, lw, poff);

    const float* ip1; const float* ip2;
    if (level == 0)      { ip1 = img1; ip2 = img2; }
    else if (level == 1) { ip1 = l1a; ip2 = l1b; }
    else if (level == 2) { ip1 = l2a; ip2 = l2b; }
    else if (level == 3) { ip1 = l3a; ip2 = l3b; }
    else                 { ip1 = l4a; ip2 = l4b; }
    ip1 += (size_t)b * W * W;
    ip2 += (size_t)b * W * W;

    float w[WS];
    gauss_weights(w);

    const int p = pbase + tid * 4;
    const int row = p >> lw;
    const int col = p - (row << lw);   // multiple of 4

    const float* r1 = ip1 + (size_t)row * W;
    const float* r2 = ip2 + (size_t)row * W;

    float f1[20], f2[20];
    if (col >= 8 && col + 12 <= W) {
#pragma unroll
        for (int k = 0; k < 5; ++k) {
            float4 a = *(const float4*)(r1 + col - 8 + 4 * k);
            float4 c = *(const float4*)(r2 + col - 8 + 4 * k);
            f1[4 * k] = a.x; f1[4 * k + 1] = a.y; f1[4 * k + 2] = a.z; f1[4 * k + 3] = a.w;
            f2[4 * k] = c.x; f2[4 * k + 1] = c.y; f2[4 * k + 2] = c.z; f2[4 * k + 3] = c.w;
        }
    } else {
#pragma unroll
        for (int k = 0; k < 5; ++k) {
#pragma unroll
            for (int u = 0; u < 4; ++u) {
                int gx = col - 8 + 4 * k + u;
                bool ok = (gx >= 0) && (gx < W);
                f1[4 * k + u] = ok ? r1[gx] : 0.f;
                f2[4 * k + u] = ok ? r2[gx] : 0.f;
            }
        }
    }

    float fs[20], fd[20];
#pragma unroll
    for (int k = 0; k < 20; ++k) {
        fs[k] = f1[k] + f2[k];
        fd[k] = f1[k] - f2[k];
    }
    float qs[14], qd[14];
#pragma unroll
    for (int k = 0; k < 14; ++k) {
        qs[k] = fs[k + 3] * fs[k + 3];
        qd[k] = fd[k + 3] * fd[k + 3];
    }
    __half2 outSD[4], outQ[4];
#pragma unroll
    for (int c = 0; c < 4; ++c) {
        float aS = 0.f, aD = 0.f, aS2 = 0.f, aD2 = 0.f;
#pragma unroll
        for (int j = 0; j < WS; ++j) {
            float wj = w[j];
            aS  = fmaf(wj, fs[3 + c + j], aS);
            aD  = fmaf(wj, fd[3 + c + j], aD);
            aS2 = fmaf(wj, qs[c + j], aS2);
            aD2 = fmaf(wj, qd[c + j], aD2);
        }
        outSD[c] = __float22half2_rn(make_float2(aS, aD));
        outQ[c]  = __float22half2_rn(make_float2(aS2, aD2));
    }
    size_t op = poff + (size_t)b * W * W + p;
    *(float4*)&pSD[op] = *(const float4*)outSD;
    *(float4*)&pQ[op]  = *(const float4*)outQ;
}

// ---------------------------------------------------------------------------
// Kernel 3: vertical pass + SSIM, all levels. 5456 blocks.
__global__ __launch_bounds__(256) void v_kernel(
    const __half2* __restrict__ pSD, const __half2* __restrict__ pQ,
    float* __restrict__ partials)
{
    __shared__ float red[2][4];
    const int tid = threadIdx.x;
    const int lin = blockIdx.x;
    int level, b, pbase, W, lw; size_t poff;
    decode_lvl(lin, level, b, pbase, W, lw, poff);

    float w[WS];
    gauss_weights(w);

    const int p = pbase + tid * 4;
    const int row = p >> lw;
    const int col = p - (row << lw);
    const size_t ibase = poff + (size_t)b * W * W;

    float aS[4] = {0.f, 0.f, 0.f, 0.f};
    float aD[4] = {0.f, 0.f, 0.f, 0.f};
    float aS2[4] = {0.f, 0.f, 0.f, 0.f};
    float aD2[4] = {0.f, 0.f, 0.f, 0.f};

#pragma unroll
    for (int j = 0; j < WS; ++j) {
        int r = row - 5 + j;
        if ((unsigned)r < (unsigned)W) {
            size_t off = ibase + ((size_t)r << lw) + col;
            float4 rawSD = *(const float4*)&pSD[off];
            float4 rawQ  = *(const float4*)&pQ[off];
            const __half2* hsd = (const __half2*)&rawSD;
            const __half2* hq  = (const __half2*)&rawQ;
            float wv = w[j];
#pragma unroll
            for (int c = 0; c < 4; ++c) {
                float2 sd = __half22float2(hsd[c]);
                float2 q  = __half22float2(hq[c]);
                aS[c]  = fmaf(wv, sd.x, aS[c]);
                aD[c]  = fmaf(wv, sd.y, aD[c]);
                aS2[c] = fmaf(wv, q.x,  aS2[c]);
                aD2[c] = fmaf(wv, q.y,  aD2[c]);
            }
        }
    }

    const float C1 = 6.5025f;    // (0.01*255)^2
    const float C2 = 58.5225f;   // (0.03*255)^2
    float sacc = 0.f, macc = 0.f;
#pragma unroll
    for (int c = 0; c < 4; ++c) {
        float ms = aS[c], md = aD[c];
        float es = aS2[c], ed = aD2[c];
        float ms2 = ms * ms, md2 = md * md;
        float a  = 0.5f * (ms2 - md2);   // 2*mu1*mu2
        float bb = 0.5f * (ms2 + md2);   // mu1^2 + mu2^2
        float pq = 0.5f * (es - ed);     // 2*E[xy]
        float qq = 0.5f * (es + ed);     // E[x^2]+E[y^2]
        float V1 = (pq - a) + C2;
        float V2 = (qq - bb) + C2;
        float num = a + C1;
        float den = bb + C1;
        float inv = 1.0f / (den * V2);
        sacc += num * V1 * inv;
        macc += V1 * den * inv;
    }

#pragma unroll
    for (int o = 32; o > 0; o >>= 1) {
        sacc += __shfl_down(sacc, o);
        macc += __shfl_down(macc, o);
    }
    int wave = tid >> 6, lane = tid & 63;
    if (lane == 0) { red[0][wave] = sacc; red[1][wave] = macc; }
    __syncthreads();
    if (tid == 0) {
        float s = red[0][0] + red[0][1] + red[0][2] + red[0][3];
        float m = red[1][0] + red[1][1] + red[1][2] + red[1][3];
        partials[2 * lin] = s;
        partials[2 * lin + 1] = m;
    }
}

// ---------------------------------------------------------------------------
__global__ __launch_bounds__(256) void finalize_kernel(
    const float* __restrict__ partials, float* __restrict__ out)
{
    __shared__ float lvl_s[5], lvl_m[5];
    __shared__ float red[2][4];
    const int nb[5] = {4096, 1024, 256, 64, 16};
    const int off[5] = {0, 4096, 5120, 5376, 5440};
    const float npix[5] = {16.f * 512 * 512, 16.f * 256 * 256, 16.f * 128 * 128,
                           16.f * 64 * 64, 16.f * 32 * 32};
    const int tid = threadIdx.x;

    for (int l = 0; l < 5; ++l) {
        float s = 0.f, m = 0.f;
        for (int i = tid; i < nb[l]; i += 256) {
            s += partials[2 * (off[l] + i)];
            m += partials[2 * (off[l] + i) + 1];
        }
#pragma unroll
        for (int o = 32; o > 0; o >>= 1) {
            s += __shfl_down(s, o);
            m += __shfl_down(m, o);
        }
        int wave = tid >> 6, lane = tid & 63;
        if (lane == 0) { red[0][wave] = s; red[1][wave] = m; }
        __syncthreads();
        if (tid == 0) {
            lvl_s[l] = (red[0][0] + red[0][1] + red[0][2] + red[0][3]) / npix[l];
            lvl_m[l] = (red[1][0] + red[1][1] + red[1][2] + red[1][3]) / npix[l];
        }
        __syncthreads();
    }

    if (tid == 0) {
        const float w[5] = {0.0448f, 0.2856f, 0.3001f, 0.2363f, 0.1333f};
        float v = powf(lvl_m[0], w[0]) * powf(lvl_m[1], w[1]) * powf(lvl_m[2], w[2]) *
                  powf(lvl_m[3], w[3]) * powf(lvl_s[4], w[4]);
        v *= 0.5f;
        v = fminf(fmaxf(v, 0.f), 1.f);
        out[0] = v;
    }
}

extern "C" void kernel_launch(void* const* d_in, const int* in_sizes, int n_in,
                              void* d_out, int out_size, void* d_ws, size_t ws_size,
                              hipStream_t stream) {
    const float* img1 = (const float*)d_in[0];
    const float* img2 = (const float*)d_in[1];
    float* out = (float*)d_out;

    const int B = 16;

    // ws layout (float units):
    //   partials: 5456*2 = 10912
    //   pooled pairs: 2*(16*256^2 + 16*128^2 + 16*64^2 + 16*32^2) = 2785280
    //   planes: pSD, pQ each 5587456 __half2 (4B) entries
    float* wsf = (float*)d_ws;
    float* partials = wsf;
    float* p = wsf + 10912;
    float* l1a = p; p += (size_t)B * 256 * 256;
    float* l1b = p; p += (size_t)B * 256 * 256;
    float* l2a = p; p += (size_t)B * 128 * 128;
    float* l2b = p; p += (size_t)B * 128 * 128;
    float* l3a = p; p += (size_t)B * 64 * 64;
    float* l3b = p; p += (size_t)B * 64 * 64;
    float* l4a = p; p += (size_t)B * 32 * 32;
    float* l4b = p; p += (size_t)B * 32 * 32;
    __half2* pSD = (__half2*)p;
    __half2* pQ  = pSD + 5587456;

    dim3 block(256);

    pool_all_kernel<<<dim3(8, 8, B), block, 0, stream>>>(
        img1, img2, l1a, l1b, l2a, l2b, l3a, l3b, l4a, l4b);

    h_kernel<<<dim3(5456), block, 0, stream>>>(
        img1, img2, l1a, l1b, l2a, l2b, l3a, l3b, l4a, l4b, pSD, pQ);

    v_kernel<<<dim3(5456), block, 0, stream>>>(pSD, pQ, partials);

    finalize_kernel<<<1, block, 0, stream>>>(partials, out);
}